// Round 4
// baseline (117.640 us; speedup 1.0000x reference)
//
#include <hip/hip_runtime.h>

#define GAMMA 0.1f
#define ETA   0.3f
#define ITERS 4   // 64-row chunks per wave

typedef __attribute__((ext_vector_type(8))) short short8;
typedef __attribute__((ext_vector_type(4))) float f32x4;

__device__ __forceinline__ short f2bf(float x) {
    // round-to-nearest-even fp32 -> bf16 payload (proven: absmax 1.56e-2)
    unsigned u = __float_as_uint(x);
    u += 0x7FFFu + ((u >> 16) & 1u);
    return (short)(u >> 16);
}

// Each wave handles ITERS*64 rows. Per 64-row chunk: lane l computes
// perm/temp/total for row base+l (coalesced stream stores), then 4 m-tiles of
// 16 rows through MFMA with SWAPPED operands (d = mfma(W2^T, h, d)) so
// lane&15 = output ROW -> LN reduces with xor16+xor32 only. b2 rides in the
// MFMA C-init. h = relu(perm*u + temp*v + b1), u=W1[0]+W1[2], v=W1[1]+W1[2]
// (feats is rank-2). Weights register-resident; no LDS, no barriers.
// __launch_bounds__(256,4): cap VGPR<=128 so 4 waves/SIMD are resident.
// Input loads are software-pipelined one chunk ahead (hide ~900cy HBM lat).
__global__ __launch_bounds__(256, 4) void market_impact_mfma(
    const float* __restrict__ os_g, const float* __restrict__ liq_g,
    const float* __restrict__ W1,  const float* __restrict__ b1g,
    const float* __restrict__ W2,  const float* __restrict__ b2,
    const float* __restrict__ lnw, const float* __restrict__ lnb,
    float* __restrict__ out, int B)
{
    const int tid  = threadIdx.x;
    const int lane = tid & 63;
    const int g    = lane >> 4;   // k-group (0..3)
    const int c    = lane & 15;   // A row = out col (within 16-block); B col = data row

    // ---- one-time per-lane weights ----
    float u[16], v[16], bb[16];
    #pragma unroll
    for (int kc = 0; kc < 2; ++kc)
        #pragma unroll
        for (int j = 0; j < 8; ++j) {
            int k = kc * 32 + g * 8 + j;
            float w0 = W1[k], w1 = W1[64 + k], w2r = W1[128 + k];
            u[kc * 8 + j]  = w0 + w2r;
            v[kc * 8 + j]  = w1 + w2r;
            bb[kc * 8 + j] = b1g[k];
        }

    // W2^T fragments (A-operand): lane m=c is output col within block cc,
    // element j <-> k = kc*32 + g*8 + j.
    short8 wfrag[2][2];
    #pragma unroll
    for (int kc = 0; kc < 2; ++kc)
        #pragma unroll
        for (int cc = 0; cc < 2; ++cc) {
            short8 t;
            #pragma unroll
            for (int j = 0; j < 8; ++j) {
                int k = kc * 32 + g * 8 + j;
                t[j] = f2bf(W2[k * 32 + cc * 16 + c]);
            }
            wfrag[kc][cc] = t;
        }

    // epilogue constants: this lane's output cols are cc*16 + g*4 + reg
    float b2a[8], lnwa[8], lnba[8];
    #pragma unroll
    for (int cc = 0; cc < 2; ++cc) {
        float4 bq = *reinterpret_cast<const float4*>(b2  + cc * 16 + g * 4);
        float4 wq = *reinterpret_cast<const float4*>(lnw + cc * 16 + g * 4);
        float4 bl = *reinterpret_cast<const float4*>(lnb + cc * 16 + g * 4);
        b2a[cc*4+0] = bq.x; b2a[cc*4+1] = bq.y; b2a[cc*4+2] = bq.z; b2a[cc*4+3] = bq.w;
        lnwa[cc*4+0] = wq.x; lnwa[cc*4+1] = wq.y; lnwa[cc*4+2] = wq.z; lnwa[cc*4+3] = wq.w;
        lnba[cc*4+0] = bl.x; lnba[cc*4+1] = bl.y; lnba[cc*4+2] = bl.z; lnba[cc*4+3] = bl.w;
    }

    const int wid = blockIdx.x * 4 + (tid >> 6);
    const long long base = (long long)wid * (ITERS * 64);
    float* enc = out + 3LL * B;

    // prefetch chunk 0
    int   pr  = (int)base + lane;
    bool  pok = (base + lane) < (long long)B;
    float o_n = pok ? os_g[pr]  : 0.f;
    float l_n = pok ? liq_g[pr] : 1.f;

    #pragma unroll 1
    for (int it = 0; it < ITERS; ++it) {
        long long cbase = base + it * 64;
        if (cbase >= B) break;                     // wave-uniform

        float o = o_n, lq = l_n;
        int   r = (int)cbase + lane;
        bool ok = r < B;

        // prefetch next chunk (issues before MFMA/LN of this chunk)
        if (it + 1 < ITERS) {
            int nr = r + 64;
            bool nok = nr < B;
            o_n = nok ? os_g[nr]  : 0.f;
            l_n = nok ? liq_g[nr] : 1.f;
        }

        // fast-approx rcp/rsq/sqrt: rel err ~1e-6 (proven absmax-neutral)
        float perm = GAMMA * o * __builtin_amdgcn_rcpf(lq);
        float temp = ETA * copysignf(__builtin_amdgcn_sqrtf(fabsf(o)), o)
                         * __builtin_amdgcn_rsqf(lq);
        if (ok) {
            out[r]         = perm;
            out[B + r]     = temp;
            out[2 * B + r] = perm + temp;
        }

        #pragma unroll
        for (int mt = 0; mt < 4; ++mt) {
            // B-operand: h for row cbase + mt*16 + c, k = kc*32 + g*8 + j
            float pm = __shfl(perm, mt * 16 + c);
            float tm = __shfl(temp, mt * 16 + c);
            short8 a0, a1;
            #pragma unroll
            for (int j = 0; j < 8; ++j) {
                float h0 = fmaxf(0.f, fmaf(pm, u[j],     fmaf(tm, v[j],     bb[j])));
                float h1 = fmaxf(0.f, fmaf(pm, u[8 + j], fmaf(tm, v[8 + j], bb[8 + j])));
                a0[j] = f2bf(h0);
                a1[j] = f2bf(h1);
            }

            // b2 rides in the accumulator init (exact: C-in of MFMA)
            f32x4 d0 = {b2a[0], b2a[1], b2a[2], b2a[3]};
            f32x4 d1 = {b2a[4], b2a[5], b2a[6], b2a[7]};
            d0 = __builtin_amdgcn_mfma_f32_16x16x32_bf16(wfrag[0][0], a0, d0, 0, 0, 0);
            d0 = __builtin_amdgcn_mfma_f32_16x16x32_bf16(wfrag[1][0], a1, d0, 0, 0, 0);
            d1 = __builtin_amdgcn_mfma_f32_16x16x32_bf16(wfrag[0][1], a0, d1, 0, 0, 0);
            d1 = __builtin_amdgcn_mfma_f32_16x16x32_bf16(wfrag[1][1], a1, d1, 0, 0, 0);

            // LN over 32 cols: lane holds row (cbase+mt*16+c), cols cc*16+g*4+reg
            float s = 0.f, q = 0.f;
            #pragma unroll
            for (int reg = 0; reg < 4; ++reg) {
                s += d0[reg];  q = fmaf(d0[reg], d0[reg], q);
                s += d1[reg];  q = fmaf(d1[reg], d1[reg], q);
            }
            s += __shfl_xor(s, 16); s += __shfl_xor(s, 32);
            q += __shfl_xor(q, 16); q += __shfl_xor(q, 32);
            float mu   = s * 0.03125f;
            float var  = fmaf(q, 0.03125f, -mu * mu);
            float rstd = __builtin_amdgcn_rsqf(var + 1e-5f);

            int row = (int)cbase + mt * 16 + c;
            if (row < B) {
                float4 o0, o1;
                o0.x = fmaf((d0[0] - mu) * rstd, lnwa[0], lnba[0]);
                o0.y = fmaf((d0[1] - mu) * rstd, lnwa[1], lnba[1]);
                o0.z = fmaf((d0[2] - mu) * rstd, lnwa[2], lnba[2]);
                o0.w = fmaf((d0[3] - mu) * rstd, lnwa[3], lnba[3]);
                o1.x = fmaf((d1[0] - mu) * rstd, lnwa[4], lnba[4]);
                o1.y = fmaf((d1[1] - mu) * rstd, lnwa[5], lnba[5]);
                o1.z = fmaf((d1[2] - mu) * rstd, lnwa[6], lnba[6]);
                o1.w = fmaf((d1[3] - mu) * rstd, lnwa[7], lnba[7]);
                float* rp = enc + (long long)row * 32;
                *reinterpret_cast<float4*>(rp + g * 4)      = o0;
                *reinterpret_cast<float4*>(rp + 16 + g * 4) = o1;
            }
        }
    }
}

extern "C" void kernel_launch(void* const* d_in, const int* in_sizes, int n_in,
                              void* d_out, int out_size, void* d_ws, size_t ws_size,
                              hipStream_t stream) {
    const float* os_g = (const float*)d_in[0];
    const float* liq  = (const float*)d_in[1];
    const float* W1   = (const float*)d_in[2];
    const float* b1   = (const float*)d_in[3];
    const float* W2   = (const float*)d_in[4];
    const float* b2   = (const float*)d_in[5];
    const float* lnw  = (const float*)d_in[6];
    const float* lnb  = (const float*)d_in[7];
    float* out = (float*)d_out;
    const int B = in_sizes[0];

    const int rows_per_block = 4 * ITERS * 64;   // 4 waves * ITERS chunks * 64 rows
    const int grid = (B + rows_per_block - 1) / rows_per_block;
    market_impact_mfma<<<grid, 256, 0, stream>>>(
        os_g, liq, W1, b1, W2, b2, lnw, lnb, out, B);
}

// Round 5
// 98.473 us; speedup vs baseline: 1.1946x; 1.1946x over previous
//
#include <hip/hip_runtime.h>

#define GAMMA 0.1f
#define ETA   0.3f
#define ITERS 2   // 64-row chunks per wave (R2 schedule — proven 86 us)

typedef __attribute__((ext_vector_type(8))) short short8;
typedef __attribute__((ext_vector_type(4))) float f32x4;

// Native bf16 conversion (RNE): clang lowers fptrunc f32->bf16 on gfx950 to
// v_cvt_pk_bf16_f32 and fuses adjacent pairs. (m240: scalar cast > hand asm.)
__device__ __forceinline__ short bfc(float x) {
    return __builtin_bit_cast(short, (__bf16)x);
}

// Each wave handles ITERS*64 rows. Per 64-row chunk: lane l computes
// perm/temp/total for row base+l (coalesced stream stores), then 4 m-tiles of
// 16 rows through MFMA with SWAPPED operands (d = mfma(W2^T, h, d)) so
// lane&15 = output ROW -> LN reduces with xor16+xor32 only. b2 rides in the
// MFMA C-init. h = relu(perm*u + temp*v + b1), u=W1[0]+W1[2], v=W1[1]+W1[2]
// (feats is rank-2). Weights register-resident; no LDS, no barriers.
__global__ __launch_bounds__(256) void market_impact_mfma(
    const float* __restrict__ os_g, const float* __restrict__ liq_g,
    const float* __restrict__ W1,  const float* __restrict__ b1g,
    const float* __restrict__ W2,  const float* __restrict__ b2,
    const float* __restrict__ lnw, const float* __restrict__ lnb,
    float* __restrict__ out, int B)
{
    const int tid  = threadIdx.x;
    const int lane = tid & 63;
    const int g    = lane >> 4;   // k-group (0..3)
    const int c    = lane & 15;   // A row = out col (within 16-block); B col = data row

    // ---- one-time per-lane weights ----
    float u[16], v[16], bb[16];
    #pragma unroll
    for (int kc = 0; kc < 2; ++kc)
        #pragma unroll
        for (int j = 0; j < 8; ++j) {
            int k = kc * 32 + g * 8 + j;
            float w0 = W1[k], w1 = W1[64 + k], w2r = W1[128 + k];
            u[kc * 8 + j]  = w0 + w2r;
            v[kc * 8 + j]  = w1 + w2r;
            bb[kc * 8 + j] = b1g[k];
        }

    // W2^T fragments (A-operand): lane m=c is output col within block cc,
    // element j <-> k = kc*32 + g*8 + j.
    short8 wfrag[2][2];
    #pragma unroll
    for (int kc = 0; kc < 2; ++kc)
        #pragma unroll
        for (int cc = 0; cc < 2; ++cc) {
            short8 t;
            #pragma unroll
            for (int j = 0; j < 8; ++j) {
                int k = kc * 32 + g * 8 + j;
                t[j] = bfc(W2[k * 32 + cc * 16 + c]);
            }
            wfrag[kc][cc] = t;
        }

    // epilogue constants: this lane's output cols are cc*16 + g*4 + reg
    float b2a[8], lnwa[8], lnba[8];
    #pragma unroll
    for (int cc = 0; cc < 2; ++cc) {
        float4 bq = *reinterpret_cast<const float4*>(b2  + cc * 16 + g * 4);
        float4 wq = *reinterpret_cast<const float4*>(lnw + cc * 16 + g * 4);
        float4 bl = *reinterpret_cast<const float4*>(lnb + cc * 16 + g * 4);
        b2a[cc*4+0] = bq.x; b2a[cc*4+1] = bq.y; b2a[cc*4+2] = bq.z; b2a[cc*4+3] = bq.w;
        lnwa[cc*4+0] = wq.x; lnwa[cc*4+1] = wq.y; lnwa[cc*4+2] = wq.z; lnwa[cc*4+3] = wq.w;
        lnba[cc*4+0] = bl.x; lnba[cc*4+1] = bl.y; lnba[cc*4+2] = bl.z; lnba[cc*4+3] = bl.w;
    }

    const long long wid = (long long)blockIdx.x * 4 + (tid >> 6);
    float* enc = out + 3LL * B;

    #pragma unroll 1
    for (int it = 0; it < ITERS; ++it) {
        long long base = (wid * ITERS + it) * 64;
        if (base >= B) break;                      // wave-uniform

        int r  = (int)base + lane;
        bool ok = r < B;
        float o  = ok ? os_g[r]  : 0.f;
        float lq = ok ? liq_g[r] : 1.f;
        // fast-approx rcp/rsq/sqrt: rel err ~1e-6 (absmax-neutral, proven R3/R4)
        float perm = GAMMA * o * __builtin_amdgcn_rcpf(lq);
        float temp = ETA * copysignf(__builtin_amdgcn_sqrtf(fabsf(o)), o)
                         * __builtin_amdgcn_rsqf(lq);
        if (ok) {
            out[r]         = perm;
            out[B + r]     = temp;
            out[2 * B + r] = perm + temp;
        }

        #pragma unroll
        for (int mt = 0; mt < 4; ++mt) {
            // B-operand: h for row base + mt*16 + c, k = kc*32 + g*8 + j
            float pm = __shfl(perm, mt * 16 + c);
            float tm = __shfl(temp, mt * 16 + c);
            short8 a0, a1;
            #pragma unroll
            for (int j = 0; j < 8; ++j) {
                float h0 = fmaxf(0.f, fmaf(pm, u[j],     fmaf(tm, v[j],     bb[j])));
                float h1 = fmaxf(0.f, fmaf(pm, u[8 + j], fmaf(tm, v[8 + j], bb[8 + j])));
                a0[j] = bfc(h0);
                a1[j] = bfc(h1);
            }

            // b2 rides in the accumulator init (exact: C-in of MFMA)
            f32x4 d0 = {b2a[0], b2a[1], b2a[2], b2a[3]};
            f32x4 d1 = {b2a[4], b2a[5], b2a[6], b2a[7]};
            d0 = __builtin_amdgcn_mfma_f32_16x16x32_bf16(wfrag[0][0], a0, d0, 0, 0, 0);
            d0 = __builtin_amdgcn_mfma_f32_16x16x32_bf16(wfrag[1][0], a1, d0, 0, 0, 0);
            d1 = __builtin_amdgcn_mfma_f32_16x16x32_bf16(wfrag[0][1], a0, d1, 0, 0, 0);
            d1 = __builtin_amdgcn_mfma_f32_16x16x32_bf16(wfrag[1][1], a1, d1, 0, 0, 0);

            // LN over 32 cols: lane holds row (base+mt*16+c), cols cc*16+g*4+reg
            float s = 0.f, q = 0.f;
            #pragma unroll
            for (int reg = 0; reg < 4; ++reg) {
                s += d0[reg];  q = fmaf(d0[reg], d0[reg], q);
                s += d1[reg];  q = fmaf(d1[reg], d1[reg], q);
            }
            s += __shfl_xor(s, 16); s += __shfl_xor(s, 32);
            q += __shfl_xor(q, 16); q += __shfl_xor(q, 32);
            float mu   = s * 0.03125f;
            float var  = fmaf(q, 0.03125f, -mu * mu);
            float rstd = __builtin_amdgcn_rsqf(var + 1e-5f);

            int row = (int)base + mt * 16 + c;
            if (row < B) {
                float4 o0, o1;
                o0.x = fmaf((d0[0] - mu) * rstd, lnwa[0], lnba[0]);
                o0.y = fmaf((d0[1] - mu) * rstd, lnwa[1], lnba[1]);
                o0.z = fmaf((d0[2] - mu) * rstd, lnwa[2], lnba[2]);
                o0.w = fmaf((d0[3] - mu) * rstd, lnwa[3], lnba[3]);
                o1.x = fmaf((d1[0] - mu) * rstd, lnwa[4], lnba[4]);
                o1.y = fmaf((d1[1] - mu) * rstd, lnwa[5], lnba[5]);
                o1.z = fmaf((d1[2] - mu) * rstd, lnwa[6], lnba[6]);
                o1.w = fmaf((d1[3] - mu) * rstd, lnwa[7], lnba[7]);
                float* rp = enc + (long long)row * 32;
                *reinterpret_cast<float4*>(rp + g * 4)      = o0;
                *reinterpret_cast<float4*>(rp + 16 + g * 4) = o1;
            }
        }
    }
}

extern "C" void kernel_launch(void* const* d_in, const int* in_sizes, int n_in,
                              void* d_out, int out_size, void* d_ws, size_t ws_size,
                              hipStream_t stream) {
    const float* os_g = (const float*)d_in[0];
    const float* liq  = (const float*)d_in[1];
    const float* W1   = (const float*)d_in[2];
    const float* b1   = (const float*)d_in[3];
    const float* W2   = (const float*)d_in[4];
    const float* b2   = (const float*)d_in[5];
    const float* lnw  = (const float*)d_in[6];
    const float* lnb  = (const float*)d_in[7];
    float* out = (float*)d_out;
    const int B = in_sizes[0];

    const int rows_per_block = 4 * ITERS * 64;   // 4 waves * ITERS chunks * 64 rows
    const int grid = (B + rows_per_block - 1) / rows_per_block;
    market_impact_mfma<<<grid, 256, 0, stream>>>(
        os_g, liq, W1, b1, W2, b2, lnw, lnb, out, B);
}

// Round 6
// 97.867 us; speedup vs baseline: 1.2020x; 1.0062x over previous
//
#include <hip/hip_runtime.h>

#define GAMMA 0.1f
#define ETA   0.3f
#define ITERS 2   // 64-row chunks per wave (R2 schedule — proven 86 us anchor)

typedef _Float16 f16x2 __attribute__((ext_vector_type(2)));
typedef _Float16 f16x8 __attribute__((ext_vector_type(8)));
typedef __attribute__((ext_vector_type(4))) float f32x4;

// Each wave handles ITERS*64 rows. Per 64-row chunk: lane l computes
// perm/temp/total for row base+l (coalesced stream stores), then 4 m-tiles of
// 16 rows through MFMA with SWAPPED operands (d = mfma(W2^T, h, d)) so
// lane&15 = output ROW -> LN reduces with xor16+xor32 only. b2 rides in the
// MFMA C-init. h = relu(perm*u + temp*v + b1), u=W1[0]+W1[2], v=W1[1]+W1[2]
// (feats is rank-2). F16 pipeline: h built with packed v_pk_fma_f16 (3 inst
// per 2 values, no cvt), consumed by mfma_f32_16x16x32_f16 (same rate/layout
// as bf16, more mantissa). Weights register-resident; no LDS, no barriers.
__global__ __launch_bounds__(256) void market_impact_mfma(
    const float* __restrict__ os_g, const float* __restrict__ liq_g,
    const float* __restrict__ W1,  const float* __restrict__ b1g,
    const float* __restrict__ W2,  const float* __restrict__ b2,
    const float* __restrict__ lnw, const float* __restrict__ lnb,
    float* __restrict__ out, int B)
{
    const int tid  = threadIdx.x;
    const int lane = tid & 63;
    const int g    = lane >> 4;   // k-group (0..3)
    const int c    = lane & 15;   // A row = out col (within 16-block); B col = data row

    // ---- one-time per-lane weights, packed f16 pairs ----
    // u2/v2/bb2[kc*4 + jj] = (val[kc*8+2jj], val[kc*8+2jj+1]), k = kc*32+g*8+j
    f16x2 u2[8], v2[8], bb2[8];
    #pragma unroll
    for (int kc = 0; kc < 2; ++kc)
        #pragma unroll
        for (int jj = 0; jj < 4; ++jj) {
            int k0 = kc * 32 + g * 8 + 2 * jj;
            float u_lo = W1[k0]     + W1[128 + k0];
            float u_hi = W1[k0 + 1] + W1[128 + k0 + 1];
            float v_lo = W1[64 + k0]     + W1[128 + k0];
            float v_hi = W1[64 + k0 + 1] + W1[128 + k0 + 1];
            u2[kc * 4 + jj]  = f16x2{(_Float16)u_lo, (_Float16)u_hi};
            v2[kc * 4 + jj]  = f16x2{(_Float16)v_lo, (_Float16)v_hi};
            bb2[kc * 4 + jj] = f16x2{(_Float16)b1g[k0], (_Float16)b1g[k0 + 1]};
        }

    // W2^T fragments (A-operand, f16): lane m=c is output col within block cc,
    // element j <-> k = kc*32 + g*8 + j.
    f16x8 wfrag[2][2];
    #pragma unroll
    for (int kc = 0; kc < 2; ++kc)
        #pragma unroll
        for (int cc = 0; cc < 2; ++cc) {
            f16x8 t;
            #pragma unroll
            for (int j = 0; j < 8; ++j) {
                int k = kc * 32 + g * 8 + j;
                t[j] = (_Float16)W2[k * 32 + cc * 16 + c];
            }
            wfrag[kc][cc] = t;
        }

    // epilogue constants: this lane's output cols are cc*16 + g*4 + reg
    float b2a[8], lnwa[8], lnba[8];
    #pragma unroll
    for (int cc = 0; cc < 2; ++cc) {
        float4 bq = *reinterpret_cast<const float4*>(b2  + cc * 16 + g * 4);
        float4 wq = *reinterpret_cast<const float4*>(lnw + cc * 16 + g * 4);
        float4 bl = *reinterpret_cast<const float4*>(lnb + cc * 16 + g * 4);
        b2a[cc*4+0] = bq.x; b2a[cc*4+1] = bq.y; b2a[cc*4+2] = bq.z; b2a[cc*4+3] = bq.w;
        lnwa[cc*4+0] = wq.x; lnwa[cc*4+1] = wq.y; lnwa[cc*4+2] = wq.z; lnwa[cc*4+3] = wq.w;
        lnba[cc*4+0] = bl.x; lnba[cc*4+1] = bl.y; lnba[cc*4+2] = bl.z; lnba[cc*4+3] = bl.w;
    }

    const long long wid = (long long)blockIdx.x * 4 + (tid >> 6);
    float* enc = out + 3LL * B;

    #pragma unroll 1
    for (int it = 0; it < ITERS; ++it) {
        long long base = (wid * ITERS + it) * 64;
        if (base >= B) break;                      // wave-uniform

        int r  = (int)base + lane;
        bool ok = r < B;
        float o  = ok ? os_g[r]  : 0.f;
        float lq = ok ? liq_g[r] : 1.f;
        float perm = GAMMA * o / lq;               // exact, as R2
        float temp = ETA * copysignf(sqrtf(fabsf(o)), o) * rsqrtf(lq);
        if (ok) {
            out[r]         = perm;
            out[B + r]     = temp;
            out[2 * B + r] = perm + temp;
        }

        #pragma unroll
        for (int mt = 0; mt < 4; ++mt) {
            // B-operand: h for row base + mt*16 + c, k = kc*32 + g*8 + j
            float pm = __shfl(perm, mt * 16 + c);
            float tm = __shfl(temp, mt * 16 + c);
            f16x2 pm2 = f16x2{(_Float16)pm, (_Float16)pm};
            f16x2 tm2 = f16x2{(_Float16)tm, (_Float16)tm};
            f16x2 z2  = f16x2{(_Float16)0.f, (_Float16)0.f};

            f16x2 h[8];
            #pragma unroll
            for (int jj = 0; jj < 8; ++jj) {
                f16x2 t = pm2 * u2[jj] + (tm2 * v2[jj] + bb2[jj]); // v_pk_fma_f16 x2
                h[jj] = __builtin_elementwise_max(t, z2);           // v_pk_max_f16
            }
            f16x8 a0 = {h[0][0], h[0][1], h[1][0], h[1][1],
                        h[2][0], h[2][1], h[3][0], h[3][1]};
            f16x8 a1 = {h[4][0], h[4][1], h[5][0], h[5][1],
                        h[6][0], h[6][1], h[7][0], h[7][1]};

            // b2 rides in the accumulator init (exact: C-in of MFMA)
            f32x4 d0 = {b2a[0], b2a[1], b2a[2], b2a[3]};
            f32x4 d1 = {b2a[4], b2a[5], b2a[6], b2a[7]};
            d0 = __builtin_amdgcn_mfma_f32_16x16x32_f16(wfrag[0][0], a0, d0, 0, 0, 0);
            d0 = __builtin_amdgcn_mfma_f32_16x16x32_f16(wfrag[1][0], a1, d0, 0, 0, 0);
            d1 = __builtin_amdgcn_mfma_f32_16x16x32_f16(wfrag[0][1], a0, d1, 0, 0, 0);
            d1 = __builtin_amdgcn_mfma_f32_16x16x32_f16(wfrag[1][1], a1, d1, 0, 0, 0);

            // LN over 32 cols: lane holds row (base+mt*16+c), cols cc*16+g*4+reg
            float s = 0.f, q = 0.f;
            #pragma unroll
            for (int reg = 0; reg < 4; ++reg) {
                s += d0[reg];  q = fmaf(d0[reg], d0[reg], q);
                s += d1[reg];  q = fmaf(d1[reg], d1[reg], q);
            }
            s += __shfl_xor(s, 16); s += __shfl_xor(s, 32);
            q += __shfl_xor(q, 16); q += __shfl_xor(q, 32);
            float mu   = s * 0.03125f;
            float var  = fmaf(q, 0.03125f, -mu * mu);
            float rstd = rsqrtf(var + 1e-5f);

            int row = (int)base + mt * 16 + c;
            if (row < B) {
                float4 o0, o1;
                o0.x = fmaf((d0[0] - mu) * rstd, lnwa[0], lnba[0]);
                o0.y = fmaf((d0[1] - mu) * rstd, lnwa[1], lnba[1]);
                o0.z = fmaf((d0[2] - mu) * rstd, lnwa[2], lnba[2]);
                o0.w = fmaf((d0[3] - mu) * rstd, lnwa[3], lnba[3]);
                o1.x = fmaf((d1[0] - mu) * rstd, lnwa[4], lnba[4]);
                o1.y = fmaf((d1[1] - mu) * rstd, lnwa[5], lnba[5]);
                o1.z = fmaf((d1[2] - mu) * rstd, lnwa[6], lnba[6]);
                o1.w = fmaf((d1[3] - mu) * rstd, lnwa[7], lnba[7]);
                float* rp = enc + (long long)row * 32;
                *reinterpret_cast<float4*>(rp + g * 4)      = o0;
                *reinterpret_cast<float4*>(rp + 16 + g * 4) = o1;
            }
        }
    }
}

extern "C" void kernel_launch(void* const* d_in, const int* in_sizes, int n_in,
                              void* d_out, int out_size, void* d_ws, size_t ws_size,
                              hipStream_t stream) {
    const float* os_g = (const float*)d_in[0];
    const float* liq  = (const float*)d_in[1];
    const float* W1   = (const float*)d_in[2];
    const float* b1   = (const float*)d_in[3];
    const float* W2   = (const float*)d_in[4];
    const float* b2   = (const float*)d_in[5];
    const float* lnw  = (const float*)d_in[6];
    const float* lnb  = (const float*)d_in[7];
    float* out = (float*)d_out;
    const int B = in_sizes[0];

    const int rows_per_block = 4 * ITERS * 64;   // 4 waves * ITERS chunks * 64 rows
    const int grid = (B + rows_per_block - 1) / rows_per_block;
    market_impact_mfma<<<grid, 256, 0, stream>>>(
        os_g, liq, W1, b1, W2, b2, lnw, lnb, out, B);
}

// Round 7
// 96.722 us; speedup vs baseline: 1.2163x; 1.0118x over previous
//
#include <hip/hip_runtime.h>

#define GAMMA 0.1f
#define ETA   0.3f
#define ITERS 4   // 64-row chunks per wave (R2 schedule, amortized 4x)

typedef __attribute__((ext_vector_type(8))) short short8;
typedef __attribute__((ext_vector_type(4))) float f32x4;

__device__ __forceinline__ short f2bf(float x) {
    // round-to-nearest-even fp32 -> bf16 payload (R2-proven: absmax 1.56e-2)
    unsigned u = __float_as_uint(x);
    u += 0x7FFFu + ((u >> 16) & 1u);
    return (short)(u >> 16);
}

// EXACT R2 structure (86 us anchor) with two isolated levers:
//   (1) ITERS 2 -> 4: amortize the ~1000-1500cy per-wave weight-load setup
//       over 4 chunks instead of 2.
//   (2) software prefetch of the NEXT chunk's os/liq (issues before this
//       chunk's MFMA/LN; hides the ~900cy HBM load latency). +4 VGPR only.
// Everything else byte-identical to R2: f2bf bit-twiddle, precise div/sqrt,
// b2 added in epilogue (NOT C-init - common factor of the ~97us regressions),
// per-mt shfl, no launch_bounds min-waves, no LDS, no barriers.
__global__ __launch_bounds__(256) void market_impact_mfma(
    const float* __restrict__ os_g, const float* __restrict__ liq_g,
    const float* __restrict__ W1,  const float* __restrict__ b1g,
    const float* __restrict__ W2,  const float* __restrict__ b2,
    const float* __restrict__ lnw, const float* __restrict__ lnb,
    float* __restrict__ out, int B)
{
    const int tid  = threadIdx.x;
    const int lane = tid & 63;
    const int g    = lane >> 4;   // k-group (0..3)
    const int c    = lane & 15;   // A row = out col (within 16-block); B col = data row

    // ---- one-time per-lane weights ----
    float u[16], v[16], bb[16];
    #pragma unroll
    for (int kc = 0; kc < 2; ++kc)
        #pragma unroll
        for (int j = 0; j < 8; ++j) {
            int k = kc * 32 + g * 8 + j;
            float w0 = W1[k], w1 = W1[64 + k], w2r = W1[128 + k];
            u[kc * 8 + j]  = w0 + w2r;
            v[kc * 8 + j]  = w1 + w2r;
            bb[kc * 8 + j] = b1g[k];
        }

    // W2^T fragments (A-operand): lane m=c is output col within block cc,
    // element j <-> k = kc*32 + g*8 + j.
    short8 wfrag[2][2];
    #pragma unroll
    for (int kc = 0; kc < 2; ++kc)
        #pragma unroll
        for (int cc = 0; cc < 2; ++cc) {
            short8 t;
            #pragma unroll
            for (int j = 0; j < 8; ++j) {
                int k = kc * 32 + g * 8 + j;
                t[j] = f2bf(W2[k * 32 + cc * 16 + c]);
            }
            wfrag[kc][cc] = t;
        }

    // epilogue constants: this lane's output cols are cc*16 + g*4 + reg
    float b2a[8], lnwa[8], lnba[8];
    #pragma unroll
    for (int cc = 0; cc < 2; ++cc) {
        float4 bq = *reinterpret_cast<const float4*>(b2  + cc * 16 + g * 4);
        float4 wq = *reinterpret_cast<const float4*>(lnw + cc * 16 + g * 4);
        float4 bl = *reinterpret_cast<const float4*>(lnb + cc * 16 + g * 4);
        b2a[cc*4+0] = bq.x; b2a[cc*4+1] = bq.y; b2a[cc*4+2] = bq.z; b2a[cc*4+3] = bq.w;
        lnwa[cc*4+0] = wq.x; lnwa[cc*4+1] = wq.y; lnwa[cc*4+2] = wq.z; lnwa[cc*4+3] = wq.w;
        lnba[cc*4+0] = bl.x; lnba[cc*4+1] = bl.y; lnba[cc*4+2] = bl.z; lnba[cc*4+3] = bl.w;
    }

    const long long wid = (long long)blockIdx.x * 4 + (tid >> 6);
    float* enc = out + 3LL * B;

    // prefetch chunk 0 inputs
    long long base0 = wid * (ITERS * 64);
    int   pr0  = (int)base0 + lane;
    bool  pok0 = (base0 + lane) < (long long)B;
    float o_n  = pok0 ? os_g[pr0]  : 0.f;
    float l_n  = pok0 ? liq_g[pr0] : 1.f;

    #pragma unroll 1
    for (int it = 0; it < ITERS; ++it) {
        long long base = base0 + it * 64;
        if (base >= B) break;                      // wave-uniform

        int r  = (int)base + lane;
        bool ok = r < B;
        float o  = o_n;
        float lq = l_n;

        // prefetch next chunk before this chunk's compute
        if (it + 1 < ITERS) {
            long long nb = base + 64;
            int nr = r + 64;
            bool nok = (nb + lane) < (long long)B;
            o_n = nok ? os_g[nr]  : 0.f;
            l_n = nok ? liq_g[nr] : 1.f;
        }

        float perm = GAMMA * o / lq;               // exact (R2)
        float temp = ETA * copysignf(sqrtf(fabsf(o)), o) * rsqrtf(lq);
        float tot  = perm + temp;
        if (ok) {
            out[r]         = perm;
            out[B + r]     = temp;
            out[2 * B + r] = tot;
        }

        #pragma unroll
        for (int mt = 0; mt < 4; ++mt) {
            // B-operand: h for row base + mt*16 + c, k = kc*32 + g*8 + j
            float pm = __shfl(perm, mt * 16 + c);
            float tm = __shfl(temp, mt * 16 + c);
            short8 a0, a1;
            #pragma unroll
            for (int j = 0; j < 8; ++j) {
                float h0 = fmaxf(0.f, fmaf(pm, u[j],     fmaf(tm, v[j],     bb[j])));
                float h1 = fmaxf(0.f, fmaf(pm, u[8 + j], fmaf(tm, v[8 + j], bb[8 + j])));
                a0[j] = f2bf(h0);
                a1[j] = f2bf(h1);
            }

            f32x4 d0 = {0.f, 0.f, 0.f, 0.f};
            f32x4 d1 = {0.f, 0.f, 0.f, 0.f};
            d0 = __builtin_amdgcn_mfma_f32_16x16x32_bf16(wfrag[0][0], a0, d0, 0, 0, 0);
            d0 = __builtin_amdgcn_mfma_f32_16x16x32_bf16(wfrag[1][0], a1, d0, 0, 0, 0);
            d1 = __builtin_amdgcn_mfma_f32_16x16x32_bf16(wfrag[0][1], a0, d1, 0, 0, 0);
            d1 = __builtin_amdgcn_mfma_f32_16x16x32_bf16(wfrag[1][1], a1, d1, 0, 0, 0);

            // x = d + b2 (epilogue, as R2); lane holds row (base+mt*16+c)
            float x[8];
            #pragma unroll
            for (int reg = 0; reg < 4; ++reg) {
                x[reg]     = d0[reg] + b2a[reg];
                x[4 + reg] = d1[reg] + b2a[4 + reg];
            }
            float s = 0.f, q = 0.f;
            #pragma unroll
            for (int j = 0; j < 8; ++j) { s += x[j]; q = fmaf(x[j], x[j], q); }
            s += __shfl_xor(s, 16); s += __shfl_xor(s, 32);
            q += __shfl_xor(q, 16); q += __shfl_xor(q, 32);
            float mu   = s * 0.03125f;
            float var  = fmaf(q, 0.03125f, -mu * mu);
            float rstd = rsqrtf(var + 1e-5f);

            int row = (int)base + mt * 16 + c;
            if (row < B) {
                float4 o0, o1;
                o0.x = fmaf((x[0] - mu) * rstd, lnwa[0], lnba[0]);
                o0.y = fmaf((x[1] - mu) * rstd, lnwa[1], lnba[1]);
                o0.z = fmaf((x[2] - mu) * rstd, lnwa[2], lnba[2]);
                o0.w = fmaf((x[3] - mu) * rstd, lnwa[3], lnba[3]);
                o1.x = fmaf((x[4] - mu) * rstd, lnwa[4], lnba[4]);
                o1.y = fmaf((x[5] - mu) * rstd, lnwa[5], lnba[5]);
                o1.z = fmaf((x[6] - mu) * rstd, lnwa[6], lnba[6]);
                o1.w = fmaf((x[7] - mu) * rstd, lnwa[7], lnba[7]);
                float* rp = enc + (long long)row * 32;
                *reinterpret_cast<float4*>(rp + g * 4)      = o0;
                *reinterpret_cast<float4*>(rp + 16 + g * 4) = o1;
            }
        }
    }
}

extern "C" void kernel_launch(void* const* d_in, const int* in_sizes, int n_in,
                              void* d_out, int out_size, void* d_ws, size_t ws_size,
                              hipStream_t stream) {
    const float* os_g = (const float*)d_in[0];
    const float* liq  = (const float*)d_in[1];
    const float* W1   = (const float*)d_in[2];
    const float* b1   = (const float*)d_in[3];
    const float* W2   = (const float*)d_in[4];
    const float* b2   = (const float*)d_in[5];
    const float* lnw  = (const float*)d_in[6];
    const float* lnb  = (const float*)d_in[7];
    float* out = (float*)d_out;
    const int B = in_sizes[0];

    const int rows_per_block = 4 * ITERS * 64;   // 4 waves * ITERS chunks * 64 rows
    const int grid = (B + rows_per_block - 1) / rows_per_block;
    market_impact_mfma<<<grid, 256, 0, stream>>>(
        os_g, liq, W1, b1, W2, b2, lnw, lnb, out, B);
}